// Round 10
// baseline (42.834 us; speedup 1.0000x reference)
//
#include <hip/hip_runtime.h>
#include <hip/hip_bf16.h>

// Locally-connected 2D: out[b,o,y,x] = sum_{c,kh,kw} x[b,c,y+kh,x+kw] * W[y,x,o,c*25+kh*5+kw] + b[y,x,o]
// x: [128,3,64,64] f32, W: [60,60,32,75] f32, bias: [60,60,32] f32, out: [128,32,60,60] f32.
//
// FUSED single kernel. Block = (y, 4-x group, b-slice of 32): 3600 blocks, 256 thr.
// Wave = one 16x16 (b,o) tile; iterates the 4 x's with accx[4] in VGPRs; final store:
// per (b,o) one aligned 16B float4 of 4 consecutive x -> direct [b,o,y,x] output.
// No tmp, no transpose kernel (kills the 88MB intermediate round trip of rounds 1-9).
// k-order k' = (c*5+kh)*8 + w, w in [0,8) = x-window offset:
// - A-fragments (8 aligned floats) loaded DIRECTLY from global per lane, packed bf16.
// - W (4 positions, contiguous 38.4KB) -> LDS via async global_load_lds width-16.
// - ONE barrier; compute loop barrier-free; B-frags = 5 ds_read_b32 + cvt +
//   compile-time xi shift-pack. cm==15 pad handled by zero A-fragment (B may read slack).
// XCD swizzle: 4 b-slice siblings + x-adjacent groups share an XCD L2 (W re-read
// served by L2/L3; 16B out-store line-merging within XCD).

#define RY 60
#define RX 60
#define OC 32
#define BATCH 128
#define CIN 3
#define HW 64

typedef __attribute__((ext_vector_type(8))) short short8;
typedef __attribute__((ext_vector_type(4))) float f32x4;

__device__ __forceinline__ ushort bf16u(float f) {
    __hip_bfloat16 h = __float2bfloat16(f);
    return *reinterpret_cast<ushort*>(&h);
}
__device__ __forceinline__ unsigned pk2(float a, float b) {
    return (unsigned)bf16u(a) | ((unsigned)bf16u(b) << 16);
}

__global__ __launch_bounds__(256, 4) void lc2d_fused(
    const float* __restrict__ x, const float* __restrict__ w,
    const float* __restrict__ bias, float* __restrict__ out)
{
    __shared__ __align__(16) float wlds[4 * 2400 + 128];   // 38912 B -> 4 blocks/CU

    const int tid = threadIdx.x;
    // bijective XCD swizzle: 3600 = 8 x 450; within an XCD chunk, b-slice fastest,
    // then x-group, then y -> siblings and x-neighbors co-located.
    const int id  = blockIdx.x;
    const int lin = (id & 7) * 450 + (id >> 3);
    const int bs  = lin & 3;                 // b-slice
    const int pg  = lin >> 2;                // 0..899
    const int y   = pg / 15;
    const int grp = pg - y * 15;
    const int x0  = grp * 4;
    const int pos0 = y * RX + x0;

    const int lane = tid & 63;
    const int wid  = tid >> 6;
    const int lrow = lane & 15;
    const int lgrp = lane >> 4;              // 0..3
    const int mt   = wid >> 1;               // 0..1
    const int nt   = wid & 1;                // 0..1
    const int bbase = bs * 32 + mt * 16;     // global b base of this wave's tile
    const int o     = nt * 16 + lrow;        // this lane's output channel

    // ---- A loads: 8 aligned float4 per lane (its 16x128 A slice) ----
    float4 av[4][2];
    #pragma unroll
    for (int ks = 0; ks < 4; ++ks) {
        const int cm = ks * 4 + lgrp;        // 0..15; 15 = zero pad
        if (cm < 15) {
            const int c  = cm / 5;
            const int kh = cm - c * 5;
            const int b  = bbase + lrow;
            const float* src = x + (size_t)((b * CIN + c) * HW + (y + kh)) * HW + x0;
            av[ks][0] = *(const float4*)(src);       // x0 % 4 == 0 -> 16B aligned
            av[ks][1] = *(const float4*)(src + 4);
        }
    }

    // ---- async W DMA: 4 positions x 2400 f32 contiguous; 38 chunks of 1KB ----
    {
        const float* gW = w + (size_t)pos0 * 2400;
        for (int j = wid; j < 38; j += 4) {
            const int chunk0 = j * 64;               // wave-uniform
            int ci = chunk0 + lane;
            if (ci > 2399) ci = 2399;                // clamp overshoot
            __builtin_amdgcn_global_load_lds(
                (const __attribute__((address_space(1))) unsigned*)(gW + ci * 4),
                (__attribute__((address_space(3))) unsigned*)&wlds[chunk0 * 4],
                16, 0, 0);
        }
    }

    // ---- bias: this lane's o at the 4 positions ----
    float bv[4];
    #pragma unroll
    for (int xi = 0; xi < 4; ++xi)
        bv[xi] = bias[(size_t)(pos0 + xi) * OC + o];

    // ---- pack A fragments (zero for the cm==15 pad slice) ----
    short8 af[4];
    #pragma unroll
    for (int ks = 0; ks < 4; ++ks) {
        const int cm = ks * 4 + lgrp;
        union { unsigned u[4]; short8 s8; } cv;
        if (cm < 15) {
            cv.u[0] = pk2(av[ks][0].x, av[ks][0].y);
            cv.u[1] = pk2(av[ks][0].z, av[ks][0].w);
            cv.u[2] = pk2(av[ks][1].x, av[ks][1].y);
            cv.u[3] = pk2(av[ks][1].z, av[ks][1].w);
        } else {
            cv.u[0] = 0u; cv.u[1] = 0u; cv.u[2] = 0u; cv.u[3] = 0u;
        }
        af[ks] = cv.s8;
    }

    __syncthreads();   // the ONLY barrier (drains W DMA)

    // ---- compute: 4 ks x 4 xi; MFMAs within a ks hit independent accx ----
    f32x4 accx[4];
    #pragma unroll
    for (int xi = 0; xi < 4; ++xi) accx[xi] = (f32x4){0.f, 0.f, 0.f, 0.f};

    const int wbase = o * 75;
    #pragma unroll
    for (int ks = 0; ks < 4; ++ks) {
        const int cm = ks * 4 + lgrp;
        const int soff = wbase + cm * 5;     // cm==15 reads slack; af==0 nullifies
        #pragma unroll
        for (int xi = 0; xi < 4; ++xi) {
            const float* s = &wlds[xi * 2400 + soff];
            const ushort h[5] = {bf16u(s[0]), bf16u(s[1]), bf16u(s[2]),
                                 bf16u(s[3]), bf16u(s[4])};
            unsigned wd[4] = {0u, 0u, 0u, 0u};
            #pragma unroll
            for (int kw = 0; kw < 5; ++kw) {
                const int ws = xi + kw;      // compile-time under unroll
                wd[ws >> 1] |= (unsigned)h[kw] << ((ws & 1) * 16);
            }
            union { unsigned u[4]; short8 s8; } cv;
            cv.u[0] = wd[0]; cv.u[1] = wd[1]; cv.u[2] = wd[2]; cv.u[3] = wd[3];
            accx[xi] = __builtin_amdgcn_mfma_f32_16x16x32_bf16(af[ks], cv.s8, accx[xi], 0, 0, 0);
        }
    }

    // ---- fused store: per (b,o) one aligned float4 of 4 consecutive x ----
    #pragma unroll
    for (int r = 0; r < 4; ++r) {
        const int bg = bbase + lgrp * 4 + r;
        float4 v;
        v.x = accx[0][r] + bv[0];
        v.y = accx[1][r] + bv[1];
        v.z = accx[2][r] + bv[2];
        v.w = accx[3][r] + bv[3];
        *(float4*)(out + (size_t)(bg * OC + o) * (RY * RX) + pos0) = v;
    }
}

extern "C" void kernel_launch(void* const* d_in, const int* in_sizes, int n_in,
                              void* d_out, int out_size, void* d_ws, size_t ws_size,
                              hipStream_t stream) {
    const float* x    = (const float*)d_in[0];
    const float* w    = (const float*)d_in[1];
    const float* bias = (const float*)d_in[2];
    float* out        = (float*)d_out;
    lc2d_fused<<<3600, 256, 0, stream>>>(x, w, bias, out);
}